// Round 3
// baseline (115.790 us; speedup 1.0000x reference)
//
#include <hip/hip_runtime.h>
#include <math.h>

#define VFS_EPS 1e-7f

constexpr int V_ = 8, F_ = 64, H_ = 256, W_ = 256, G_ = 128, S_ = 512;
constexpr int HW_ = H_ * W_;

// -------- K0: register transpose [V][F][HW] -> [V][HW][F], no LDS --------
// lane = (p4, cql): 16 pixels x 4 channel-quads per wave; wave w owns channels
// [16w, 16w+16). Loads: 64B-contiguous per (channel,j); store: float4, 4 lanes
// fill a 64B line. No LDS, no barriers -> pure streaming.
__global__ __launch_bounds__(256) void vfs_transpose(const float* __restrict__ src,
                                                     float* __restrict__ dst) {
    const int v = blockIdx.y;
    const int p0 = blockIdx.x * 64;
    const int t = threadIdx.x;
    const int wave = t >> 6;
    const int p4 = (t & 63) >> 2;
    const int cql = t & 3;
    const int cbase = wave * 16 + cql * 4;  // first channel of this thread's quad
    const float* s = src + (size_t)v * F_ * HW_;
    float* d = dst + (size_t)v * HW_ * F_;
#pragma unroll
    for (int i = 0; i < 4; ++i) {
        const int p = p0 + i * 16 + p4;
        float4 val;
        val.x = s[(size_t)(cbase + 0) * HW_ + p];
        val.y = s[(size_t)(cbase + 1) * HW_ + p];
        val.z = s[(size_t)(cbase + 2) * HW_ + p];
        val.w = s[(size_t)(cbase + 3) * HW_ + p];
        *reinterpret_cast<float4*>(&d[(size_t)p * F_ + cbase]) = val;
    }
}

// -------- K1: project + weight + bilinear sample + weighted mean/var --------
// PS = pixel stride (elements), CS = channel stride. Transposed: PS=F, CS=1.
template <int PS, int CS>
__global__ __launch_bounds__(256) void vfs_sampler(
    const float* __restrict__ feat,
    const float* __restrict__ Km, const float* __restrict__ Em,
    const float* __restrict__ dst, const float* __restrict__ grids,
    const float* __restrict__ vis, const float* __restrict__ normals,
    const float* __restrict__ cc, float* __restrict__ out) {
    __shared__ float4 wp[64][8];   // {x0 bits, y0 bits, wx, wy} per (s_local, view)
    __shared__ float wv[64][8];    // normalized view weight
    __shared__ float stg[64][65];  // staging for coalesced writeout

    const int g = blockIdx.x >> 3;
    const int sb = (blockIdx.x & 7) * 64;
    const int t = threadIdx.x;
    const int wave = t >> 6;
    const int lane = t & 63;
    const int vL = lane & 7;   // view
    const int pL = lane >> 3;  // point-in-group

    const float nx = normals[g * 3 + 0];
    const float ny = normals[g * 3 + 1];
    const float nz = normals[g * 3 + 2];

    // ---- Phase A: per (point, view) sampling params + normalized weights ----
#pragma unroll
    for (int grp = 0; grp < 2; ++grp) {
        const int sl = wave * 16 + grp * 8 + pL;
        const int s = sb + sl;
        const float px = grids[(g * 3 + 0) * S_ + s];
        const float py = grids[(g * 3 + 1) * S_ + s];
        const float pz = grids[(g * 3 + 2) * S_ + s];
        const float* Ev = Em + vL * 12;
        const float pi0 = Ev[0] * px + Ev[1] * py + Ev[2] * pz + Ev[3];
        const float pi1 = Ev[4] * px + Ev[5] * py + Ev[6] * pz + Ev[7];
        float z = Ev[8] * px + Ev[9] * py + Ev[10] * pz + Ev[11];
        if (fabsf(z) < VFS_EPS) z = 1.0f;
        const float xn = pi0 / z;
        const float yn = pi1 / z;
        const float r2 = xn * xn + yn * yn;
        const float fd = 1.0f + dst[vL * 2 + 0] * r2 + dst[vL * 2 + 1] * r2 * r2;
        const float xd = xn * fd, yd = yn * fd;
        const float* Kv = Km + vL * 9;
        const float pk0 = Kv[0] * xd + Kv[1] * yd + Kv[2];
        const float pk1 = Kv[3] * xd + Kv[4] * yd + Kv[5];
        const float u = 2.0f * pk0 / (W_ - 1.0f) - 1.0f;
        const float vq = 2.0f * pk1 / (H_ - 1.0f) - 1.0f;
        const bool inside = (u >= -1.0f) && (u <= 1.0f) && (vq >= -1.0f) && (vq <= 1.0f);
        const float x = (u + 1.0f) * (W_ * 0.5f) - 0.5f;
        const float y = (vq + 1.0f) * (H_ * 0.5f) - 0.5f;
        const float x0f = floorf(x), y0f = floorf(y);
        const float wx = x - x0f, wy = y - y0f;
        const int x0 = (int)x0f, y0 = (int)y0f;
        // view-direction / normal incidence
        const float dx = px - cc[vL * 3 + 0];
        const float dy = py - cc[vL * 3 + 1];
        const float dz = pz - cc[vL * 3 + 2];
        float nrm = sqrtf(dx * dx + dy * dy + dz * dz);
        nrm = fmaxf(nrm, 1e-12f);
        float cosv = (dx * nx + dy * ny + dz * nz) / nrm;
        cosv = fminf(cosv, 0.0f);
        const float wraw = vis[vL * G_ + g] * (-cosv) * (inside ? 1.0f : 0.0f);
        const float bx = 50.0f * wraw;
        float w = (bx > 5.0f) ? wraw : (log1pf(expf(bx)) * (1.0f / 50.0f));
        // normalize over the 8 views (lanes sharing pL)
        float wsum = w;
        wsum += __shfl_xor(wsum, 1);
        wsum += __shfl_xor(wsum, 2);
        wsum += __shfl_xor(wsum, 4);
        w = w / wsum;
        wp[sl][vL] = make_float4(__int_as_float(x0), __int_as_float(y0), wx, wy);
        wv[sl][vL] = w;
    }
    __syncthreads();

    // ---- Phase B: lane = channel; branchless clamped gather + accumulate ----
    float mean[16], var[16];
#pragma unroll 2
    for (int j = 0; j < 16; ++j) {
        const int sl = wave * 16 + j;
        float m = 0.0f, m2 = 0.0f;
#pragma unroll
        for (int v = 0; v < 8; ++v) {
            const float4 q = wp[sl][v];       // broadcast (uniform across wave)
            const float w = wv[sl][v];
            const int x0 = __float_as_int(q.x);
            const int y0 = __float_as_int(q.y);
            const float wx = q.z, wy = q.w;
            const bool vx0 = (x0 >= 0) & (x0 < W_);
            const bool vx1 = (x0 >= -1) & (x0 < W_ - 1);
            const bool vy0 = (y0 >= 0) & (y0 < H_);
            const bool vy1 = (y0 >= -1) & (y0 < H_ - 1);
            const int xc0 = min(max(x0, 0), W_ - 1);
            const int xc1 = min(max(x0 + 1, 0), W_ - 1);
            const int yc0 = min(max(y0, 0), H_ - 1);
            const int yc1 = min(max(y0 + 1, 0), H_ - 1);
            const float* base = feat + (size_t)v * ((size_t)HW_ * F_) + (size_t)lane * CS;
            const float g00 = base[(size_t)(yc0 * W_ + xc0) * PS];
            const float g01 = base[(size_t)(yc0 * W_ + xc1) * PS];
            const float g10 = base[(size_t)(yc1 * W_ + xc0) * PS];
            const float g11 = base[(size_t)(yc1 * W_ + xc1) * PS];
            const float f00 = (vx0 & vy0) ? (1.f - wx) * (1.f - wy) : 0.f;
            const float f01 = (vx1 & vy0) ? wx * (1.f - wy) : 0.f;
            const float f10 = (vx0 & vy1) ? (1.f - wx) * wy : 0.f;
            const float f11 = (vx1 & vy1) ? wx * wy : 0.f;
            const float fe = g00 * f00 + g01 * f01 + g10 * f10 + g11 * f11;
            m += w * fe;
            m2 += w * fe * fe;
        }
        mean[j] = m;
        var[j] = m2 - m * m;
    }

    // ---- coalesced write-out via single staging buffer, two passes ----
#pragma unroll
    for (int j = 0; j < 16; ++j) stg[wave * 16 + j][lane] = mean[j];
    __syncthreads();
#pragma unroll
    for (int i = 0; i < 16; ++i) {
        const int e = t + i * 256;
        const int f = e >> 6;
        const int sl = e & 63;
        out[((size_t)(g * 2 * F_ + f)) * S_ + sb + sl] = stg[sl][f];
    }
    __syncthreads();
#pragma unroll
    for (int j = 0; j < 16; ++j) stg[wave * 16 + j][lane] = var[j];
    __syncthreads();
#pragma unroll
    for (int i = 0; i < 16; ++i) {
        const int e = t + i * 256;
        const int f = e >> 6;
        const int sl = e & 63;
        out[((size_t)(g * 2 * F_ + F_ + f)) * S_ + sb + sl] = stg[sl][f];
    }
}

extern "C" void kernel_launch(void* const* d_in, const int* in_sizes, int n_in,
                              void* d_out, int out_size, void* d_ws, size_t ws_size,
                              hipStream_t stream) {
    const float* fm      = (const float*)d_in[0]; // [1][8][64][256][256]
    const float* Km      = (const float*)d_in[1]; // [1][8][3][3]
    const float* Em      = (const float*)d_in[2]; // [1][8][3][4]
    const float* dist    = (const float*)d_in[3]; // [1][8][2]
    const float* grids   = (const float*)d_in[4]; // [1][128][3][8][8][8]
    const float* vis     = (const float*)d_in[5]; // [1][8][128]
    const float* normals = (const float*)d_in[6]; // [1][128][3]
    const float* cc      = (const float*)d_in[7]; // [1][8][3]
    float* out           = (float*)d_out;         // [1][128][128][8][8][8]

    const size_t tsize = (size_t)V_ * F_ * HW_ * sizeof(float); // 128 MB
    if (ws_size >= tsize) {
        vfs_transpose<<<dim3(HW_ / 64, V_), 256, 0, stream>>>(fm, (float*)d_ws);
        vfs_sampler<F_, 1><<<G_ * 8, 256, 0, stream>>>((const float*)d_ws, Km, Em, dist,
                                                       grids, vis, normals, cc, out);
    } else {
        vfs_sampler<1, HW_><<<G_ * 8, 256, 0, stream>>>(fm, Km, Em, dist,
                                                        grids, vis, normals, cc, out);
    }
}

// Round 4
// 104.235 us; speedup vs baseline: 1.1109x; 1.1109x over previous
//
#include <hip/hip_runtime.h>
#include <hip/hip_fp16.h>
#include <math.h>

#define VFS_EPS 1e-7f

constexpr int V_ = 8, F_ = 64, H_ = 256, W_ = 256, G_ = 128, S_ = 512;
constexpr int HW_ = H_ * W_;
constexpr int TPX = 512;  // pixels per transpose tile

// -------- K0: transpose+convert [V][F][HW] f32 -> [V][HW][F] f16 --------
// Block = 512 threads, owns 512 px x 64 ch. Phase 1: each channel read as one
// 2KB contiguous run (DRAM-friendly). Phase 2: 64KB contiguous store.
// LDS layout: element (p,c) lives at row p, octet (c>>3)^(p&7), slot c&7 --
// makes phase-2 ds_read_b128 conflict-free (octets bijective per 8 lanes).
__global__ __launch_bounds__(512) void vfs_transpose_h(const float* __restrict__ src,
                                                       __half* __restrict__ dst) {
    __shared__ ushort L[TPX][64];  // 64 KB
    const int v = blockIdx.y;
    const int p0 = blockIdx.x * TPX;
    const int t = threadIdx.x;
    const float* s = src + (size_t)v * F_ * HW_ + p0;
    // phase 1: iterate channels; thread t handles pixel t of each channel
#pragma unroll 8
    for (int c = 0; c < F_; ++c) {
        const float val = s[(size_t)c * HW_ + t];
        const int os = (c >> 3) ^ (t & 7);
        L[t][os * 8 + (c & 7)] = __half_as_ushort(__float2half(val));
    }
    __syncthreads();
    // phase 2: flat 16B chunks over [512 px][128 B]
    __half* d = dst + ((size_t)v * HW_ + p0) * F_;
#pragma unroll
    for (int i = 0; i < 8; ++i) {
        const int j = i * 512 + t;
        const int p = j >> 3;
        const int o = j & 7;
        const int os = o ^ (p & 7);
        const uint4 val = *reinterpret_cast<const uint4*>(&L[p][os * 8]);
        *reinterpret_cast<uint4*>(&d[(size_t)j * 8]) = val;
    }
}

__device__ __forceinline__ float vfs_ldf(const float* p) { return *p; }
__device__ __forceinline__ float vfs_ldf(const __half* p) { return __half2float(*p); }

// -------- K1: project + weight + bilinear sample + weighted mean/var --------
// PS = pixel stride (elements), CS = channel stride. Transposed: PS=F, CS=1.
template <typename T, int PS, int CS>
__global__ __launch_bounds__(256) void vfs_sampler(
    const T* __restrict__ feat,
    const float* __restrict__ Km, const float* __restrict__ Em,
    const float* __restrict__ dst, const float* __restrict__ grids,
    const float* __restrict__ vis, const float* __restrict__ normals,
    const float* __restrict__ cc, float* __restrict__ out) {
    __shared__ float4 wp[64][8];   // {x0 bits, y0 bits, wx, wy} per (s_local, view)
    __shared__ float wv[64][8];    // normalized view weight
    __shared__ float stg[64][65];  // staging for coalesced writeout

    const int g = blockIdx.x >> 3;
    const int sb = (blockIdx.x & 7) * 64;
    const int t = threadIdx.x;
    const int wave = t >> 6;
    const int lane = t & 63;
    const int vL = lane & 7;   // view
    const int pL = lane >> 3;  // point-in-group

    const float nx = normals[g * 3 + 0];
    const float ny = normals[g * 3 + 1];
    const float nz = normals[g * 3 + 2];

    // ---- Phase A: per (point, view) sampling params + normalized weights ----
#pragma unroll
    for (int grp = 0; grp < 2; ++grp) {
        const int sl = wave * 16 + grp * 8 + pL;
        const int s = sb + sl;
        const float px = grids[(g * 3 + 0) * S_ + s];
        const float py = grids[(g * 3 + 1) * S_ + s];
        const float pz = grids[(g * 3 + 2) * S_ + s];
        const float* Ev = Em + vL * 12;
        const float pi0 = Ev[0] * px + Ev[1] * py + Ev[2] * pz + Ev[3];
        const float pi1 = Ev[4] * px + Ev[5] * py + Ev[6] * pz + Ev[7];
        float z = Ev[8] * px + Ev[9] * py + Ev[10] * pz + Ev[11];
        if (fabsf(z) < VFS_EPS) z = 1.0f;
        const float xn = pi0 / z;
        const float yn = pi1 / z;
        const float r2 = xn * xn + yn * yn;
        const float fd = 1.0f + dst[vL * 2 + 0] * r2 + dst[vL * 2 + 1] * r2 * r2;
        const float xd = xn * fd, yd = yn * fd;
        const float* Kv = Km + vL * 9;
        const float pk0 = Kv[0] * xd + Kv[1] * yd + Kv[2];
        const float pk1 = Kv[3] * xd + Kv[4] * yd + Kv[5];
        const float u = 2.0f * pk0 / (W_ - 1.0f) - 1.0f;
        const float vq = 2.0f * pk1 / (H_ - 1.0f) - 1.0f;
        const bool inside = (u >= -1.0f) && (u <= 1.0f) && (vq >= -1.0f) && (vq <= 1.0f);
        const float x = (u + 1.0f) * (W_ * 0.5f) - 0.5f;
        const float y = (vq + 1.0f) * (H_ * 0.5f) - 0.5f;
        const float x0f = floorf(x), y0f = floorf(y);
        const float wx = x - x0f, wy = y - y0f;
        const int x0 = (int)x0f, y0 = (int)y0f;
        // view-direction / normal incidence
        const float dx = px - cc[vL * 3 + 0];
        const float dy = py - cc[vL * 3 + 1];
        const float dz = pz - cc[vL * 3 + 2];
        float nrm = sqrtf(dx * dx + dy * dy + dz * dz);
        nrm = fmaxf(nrm, 1e-12f);
        float cosv = (dx * nx + dy * ny + dz * nz) / nrm;
        cosv = fminf(cosv, 0.0f);
        const float wraw = vis[vL * G_ + g] * (-cosv) * (inside ? 1.0f : 0.0f);
        const float bx = 50.0f * wraw;
        float w = (bx > 5.0f) ? wraw : (log1pf(expf(bx)) * (1.0f / 50.0f));
        // normalize over the 8 views (lanes sharing pL)
        float wsum = w;
        wsum += __shfl_xor(wsum, 1);
        wsum += __shfl_xor(wsum, 2);
        wsum += __shfl_xor(wsum, 4);
        w = w / wsum;
        wp[sl][vL] = make_float4(__int_as_float(x0), __int_as_float(y0), wx, wy);
        wv[sl][vL] = w;
    }
    __syncthreads();

    // ---- Phase B: lane = channel; branchless clamped gather + accumulate ----
    float mean[16], var[16];
#pragma unroll 2
    for (int j = 0; j < 16; ++j) {
        const int sl = wave * 16 + j;
        float m = 0.0f, m2 = 0.0f;
#pragma unroll
        for (int v = 0; v < 8; ++v) {
            const float4 q = wp[sl][v];       // broadcast (uniform across wave)
            const float w = wv[sl][v];
            const int x0 = __float_as_int(q.x);
            const int y0 = __float_as_int(q.y);
            const float wx = q.z, wy = q.w;
            const bool vx0 = (x0 >= 0) & (x0 < W_);
            const bool vx1 = (x0 >= -1) & (x0 < W_ - 1);
            const bool vy0 = (y0 >= 0) & (y0 < H_);
            const bool vy1 = (y0 >= -1) & (y0 < H_ - 1);
            const int xc0 = min(max(x0, 0), W_ - 1);
            const int xc1 = min(max(x0 + 1, 0), W_ - 1);
            const int yc0 = min(max(y0, 0), H_ - 1);
            const int yc1 = min(max(y0 + 1, 0), H_ - 1);
            const T* base = feat + (size_t)v * ((size_t)HW_ * F_) + (size_t)lane * CS;
            const float g00 = vfs_ldf(&base[(size_t)(yc0 * W_ + xc0) * PS]);
            const float g01 = vfs_ldf(&base[(size_t)(yc0 * W_ + xc1) * PS]);
            const float g10 = vfs_ldf(&base[(size_t)(yc1 * W_ + xc0) * PS]);
            const float g11 = vfs_ldf(&base[(size_t)(yc1 * W_ + xc1) * PS]);
            const float f00 = (vx0 & vy0) ? (1.f - wx) * (1.f - wy) : 0.f;
            const float f01 = (vx1 & vy0) ? wx * (1.f - wy) : 0.f;
            const float f10 = (vx0 & vy1) ? (1.f - wx) * wy : 0.f;
            const float f11 = (vx1 & vy1) ? wx * wy : 0.f;
            const float fe = g00 * f00 + g01 * f01 + g10 * f10 + g11 * f11;
            m += w * fe;
            m2 += w * fe * fe;
        }
        mean[j] = m;
        var[j] = m2 - m * m;
    }

    // ---- coalesced write-out via single staging buffer, two passes ----
#pragma unroll
    for (int j = 0; j < 16; ++j) stg[wave * 16 + j][lane] = mean[j];
    __syncthreads();
#pragma unroll
    for (int i = 0; i < 16; ++i) {
        const int e = t + i * 256;
        const int f = e >> 6;
        const int sl = e & 63;
        out[((size_t)(g * 2 * F_ + f)) * S_ + sb + sl] = stg[sl][f];
    }
    __syncthreads();
#pragma unroll
    for (int j = 0; j < 16; ++j) stg[wave * 16 + j][lane] = var[j];
    __syncthreads();
#pragma unroll
    for (int i = 0; i < 16; ++i) {
        const int e = t + i * 256;
        const int f = e >> 6;
        const int sl = e & 63;
        out[((size_t)(g * 2 * F_ + F_ + f)) * S_ + sb + sl] = stg[sl][f];
    }
}

extern "C" void kernel_launch(void* const* d_in, const int* in_sizes, int n_in,
                              void* d_out, int out_size, void* d_ws, size_t ws_size,
                              hipStream_t stream) {
    const float* fm      = (const float*)d_in[0]; // [1][8][64][256][256]
    const float* Km      = (const float*)d_in[1]; // [1][8][3][3]
    const float* Em      = (const float*)d_in[2]; // [1][8][3][4]
    const float* dist    = (const float*)d_in[3]; // [1][8][2]
    const float* grids   = (const float*)d_in[4]; // [1][128][3][8][8][8]
    const float* vis     = (const float*)d_in[5]; // [1][8][128]
    const float* normals = (const float*)d_in[6]; // [1][128][3]
    const float* cc      = (const float*)d_in[7]; // [1][8][3]
    float* out           = (float*)d_out;         // [1][128][128][8][8][8]

    const size_t tsize = (size_t)V_ * F_ * HW_ * sizeof(__half); // 67 MB
    if (ws_size >= tsize) {
        vfs_transpose_h<<<dim3(HW_ / TPX, V_), 512, 0, stream>>>(fm, (__half*)d_ws);
        vfs_sampler<__half, F_, 1><<<G_ * 8, 256, 0, stream>>>(
            (const __half*)d_ws, Km, Em, dist, grids, vis, normals, cc, out);
    } else {
        vfs_sampler<float, 1, HW_><<<G_ * 8, 256, 0, stream>>>(
            fm, Km, Em, dist, grids, vis, normals, cc, out);
    }
}

// Round 5
// 76.709 us; speedup vs baseline: 1.5095x; 1.3588x over previous
//
#include <hip/hip_runtime.h>
#include <hip/hip_fp16.h>
#include <math.h>

#define VFS_EPS 1e-7f

constexpr int V_ = 8, F_ = 64, H_ = 256, W_ = 256, G_ = 128, S_ = 512;
constexpr int HW_ = H_ * W_;
constexpr int TPX = 512;  // pixels per transpose tile

// -------- K0: transpose+convert [V][F][HW] f32 -> [V][HW][F] f16 --------
// Block = 512 threads, owns 512 px x 64 ch. Phase 1: each channel read as one
// 2KB contiguous run (DRAM-friendly). Phase 2: 64KB contiguous store.
// Validated R4: ~27 us.
__global__ __launch_bounds__(512) void vfs_transpose_h(const float* __restrict__ src,
                                                       __half* __restrict__ dst) {
    __shared__ ushort L[TPX][64];  // 64 KB
    const int v = blockIdx.y;
    const int p0 = blockIdx.x * TPX;
    const int t = threadIdx.x;
    const float* s = src + (size_t)v * F_ * HW_ + p0;
#pragma unroll 8
    for (int c = 0; c < F_; ++c) {
        const float val = s[(size_t)c * HW_ + t];
        const int os = (c >> 3) ^ (t & 7);
        L[t][os * 8 + (c & 7)] = __half_as_ushort(__float2half(val));
    }
    __syncthreads();
    __half* d = dst + ((size_t)v * HW_ + p0) * F_;
#pragma unroll
    for (int i = 0; i < 8; ++i) {
        const int j = i * 512 + t;
        const int p = j >> 3;
        const int o = j & 7;
        const int os = o ^ (p & 7);
        const uint4 val = *reinterpret_cast<const uint4*>(&L[p][os * 8]);
        *reinterpret_cast<uint4*>(&d[(size_t)j * 8]) = val;
    }
}

// -------- K1 (f16 ws): wave = 2 points x 32 channel-pairs, __half2 gathers --------
__global__ __launch_bounds__(256) void vfs_sampler_h2(
    const __half* __restrict__ feat,
    const float* __restrict__ Km, const float* __restrict__ Em,
    const float* __restrict__ dst, const float* __restrict__ grids,
    const float* __restrict__ vis, const float* __restrict__ normals,
    const float* __restrict__ cc, float* __restrict__ out) {
    __shared__ float4 wp[64][8];   // {x0 bits, y0 bits, wx, wy} per (s_local, view)
    __shared__ float wv[64][8];    // normalized view weight
    __shared__ float stgM[64][65]; // mean staging (padded, conflict-free readout)
    __shared__ float stgV[64][65]; // var staging

    const int g = blockIdx.x >> 3;
    const int sb = (blockIdx.x & 7) * 64;
    const int t = threadIdx.x;
    const int wave = t >> 6;
    const int lane = t & 63;

    // ---- Phase A: lane = (point8, view8); params + normalized weights ----
    {
        const int vL = lane & 7;
        const int pL = lane >> 3;
        const float nx = normals[g * 3 + 0];
        const float ny = normals[g * 3 + 1];
        const float nz = normals[g * 3 + 2];
#pragma unroll
        for (int grp = 0; grp < 2; ++grp) {
            const int sl = wave * 16 + grp * 8 + pL;
            const int s = sb + sl;
            const float px = grids[(g * 3 + 0) * S_ + s];
            const float py = grids[(g * 3 + 1) * S_ + s];
            const float pz = grids[(g * 3 + 2) * S_ + s];
            const float* Ev = Em + vL * 12;
            const float pi0 = Ev[0] * px + Ev[1] * py + Ev[2] * pz + Ev[3];
            const float pi1 = Ev[4] * px + Ev[5] * py + Ev[6] * pz + Ev[7];
            float z = Ev[8] * px + Ev[9] * py + Ev[10] * pz + Ev[11];
            if (fabsf(z) < VFS_EPS) z = 1.0f;
            const float xn = pi0 / z;
            const float yn = pi1 / z;
            const float r2 = xn * xn + yn * yn;
            const float fd = 1.0f + dst[vL * 2 + 0] * r2 + dst[vL * 2 + 1] * r2 * r2;
            const float xd = xn * fd, yd = yn * fd;
            const float* Kv = Km + vL * 9;
            const float pk0 = Kv[0] * xd + Kv[1] * yd + Kv[2];
            const float pk1 = Kv[3] * xd + Kv[4] * yd + Kv[5];
            const float u = 2.0f * pk0 / (W_ - 1.0f) - 1.0f;
            const float vq = 2.0f * pk1 / (H_ - 1.0f) - 1.0f;
            const bool inside = (u >= -1.0f) && (u <= 1.0f) && (vq >= -1.0f) && (vq <= 1.0f);
            const float x = (u + 1.0f) * (W_ * 0.5f) - 0.5f;
            const float y = (vq + 1.0f) * (H_ * 0.5f) - 0.5f;
            const float x0f = floorf(x), y0f = floorf(y);
            const float wx = x - x0f, wy = y - y0f;
            const int x0 = (int)x0f, y0 = (int)y0f;
            const float dx = px - cc[vL * 3 + 0];
            const float dy = py - cc[vL * 3 + 1];
            const float dz = pz - cc[vL * 3 + 2];
            float nrm = sqrtf(dx * dx + dy * dy + dz * dz);
            nrm = fmaxf(nrm, 1e-12f);
            float cosv = (dx * nx + dy * ny + dz * nz) / nrm;
            cosv = fminf(cosv, 0.0f);
            const float wraw = vis[vL * G_ + g] * (-cosv) * (inside ? 1.0f : 0.0f);
            const float bx = 50.0f * wraw;
            float w = (bx > 5.0f) ? wraw : (log1pf(expf(bx)) * (1.0f / 50.0f));
            float wsum = w;
            wsum += __shfl_xor(wsum, 1);
            wsum += __shfl_xor(wsum, 2);
            wsum += __shfl_xor(wsum, 4);
            w = w / wsum;
            wp[sl][vL] = make_float4(__int_as_float(x0), __int_as_float(y0), wx, wy);
            wv[sl][vL] = w;
        }
    }
    __syncthreads();

    // ---- Phase B: wave = 2 points x 32 channel-pairs; dword __half2 gathers ----
    const int sub = lane >> 5;  // which point of the pair
    const int cp = lane & 31;   // channel pair -> channels 2cp, 2cp+1
    const uint* fp = reinterpret_cast<const uint*>(feat);
    for (int jj = 0; jj < 8; ++jj) {
        const int sl = wave * 16 + jj * 2 + sub;
        float mx = 0.f, my = 0.f, qx = 0.f, qy = 0.f;
#pragma unroll
        for (int v = 0; v < 8; ++v) {
            const float4 q = wp[sl][v];   // broadcast within half-wave
            const float w = wv[sl][v];
            const int x0 = __float_as_int(q.x);
            const int y0 = __float_as_int(q.y);
            const float wx = q.z, wy = q.w;
            const bool vx0 = (x0 >= 0) & (x0 < W_);
            const bool vx1 = (x0 >= -1) & (x0 < W_ - 1);
            const bool vy0 = (y0 >= 0) & (y0 < H_);
            const bool vy1 = (y0 >= -1) & (y0 < H_ - 1);
            const int xc0 = min(max(x0, 0), W_ - 1);
            const int xc1 = min(max(x0 + 1, 0), W_ - 1);
            const int yc0 = min(max(y0, 0), H_ - 1);
            const int yc1 = min(max(y0 + 1, 0), H_ - 1);
            const uint base = (uint)(v * HW_) * 32u + (uint)cp;
            const uint i00 = base + (uint)(yc0 * W_ + xc0) * 32u;
            const uint i01 = base + (uint)(yc0 * W_ + xc1) * 32u;
            const uint i10 = base + (uint)(yc1 * W_ + xc0) * 32u;
            const uint i11 = base + (uint)(yc1 * W_ + xc1) * 32u;
            const float2 g00 = __half22float2(*reinterpret_cast<const __half2*>(fp + i00));
            const float2 g01 = __half22float2(*reinterpret_cast<const __half2*>(fp + i01));
            const float2 g10 = __half22float2(*reinterpret_cast<const __half2*>(fp + i10));
            const float2 g11 = __half22float2(*reinterpret_cast<const __half2*>(fp + i11));
            const float f00 = (vx0 & vy0) ? (1.f - wx) * (1.f - wy) : 0.f;
            const float f01 = (vx1 & vy0) ? wx * (1.f - wy) : 0.f;
            const float f10 = (vx0 & vy1) ? (1.f - wx) * wy : 0.f;
            const float f11 = (vx1 & vy1) ? wx * wy : 0.f;
            const float fex = g00.x * f00 + g01.x * f01 + g10.x * f10 + g11.x * f11;
            const float fey = g00.y * f00 + g01.y * f01 + g10.y * f10 + g11.y * f11;
            mx += w * fex;
            qx += w * fex * fex;
            my += w * fey;
            qy += w * fey * fey;
        }
        stgM[sl][2 * cp + 0] = mx;
        stgM[sl][2 * cp + 1] = my;
        stgV[sl][2 * cp + 0] = qx - mx * mx;
        stgV[sl][2 * cp + 1] = qy - my * my;
    }
    __syncthreads();

    // ---- coalesced write-out ----
#pragma unroll
    for (int i = 0; i < 16; ++i) {
        const int e = t + i * 256;
        const int f = e >> 6;
        const int sl = e & 63;
        out[((size_t)(g * 2 * F_ + f)) * S_ + sb + sl] = stgM[sl][f];
    }
#pragma unroll
    for (int i = 0; i < 16; ++i) {
        const int e = t + i * 256;
        const int f = e >> 6;
        const int sl = e & 63;
        out[((size_t)(g * 2 * F_ + F_ + f)) * S_ + sb + sl] = stgV[sl][f];
    }
}

// -------- K1 fallback (raw f32 layout), from R2 (validated) --------
__global__ __launch_bounds__(256) void vfs_sampler_f32(
    const float* __restrict__ feat,
    const float* __restrict__ Km, const float* __restrict__ Em,
    const float* __restrict__ dst, const float* __restrict__ grids,
    const float* __restrict__ vis, const float* __restrict__ normals,
    const float* __restrict__ cc, float* __restrict__ out) {
    __shared__ float4 wp[64][8];
    __shared__ float wv[64][8];
    __shared__ float stg[64][65];

    const int g = blockIdx.x >> 3;
    const int sb = (blockIdx.x & 7) * 64;
    const int t = threadIdx.x;
    const int wave = t >> 6;
    const int lane = t & 63;
    const int vL = lane & 7;
    const int pL = lane >> 3;

    const float nx = normals[g * 3 + 0];
    const float ny = normals[g * 3 + 1];
    const float nz = normals[g * 3 + 2];

#pragma unroll
    for (int grp = 0; grp < 2; ++grp) {
        const int sl = wave * 16 + grp * 8 + pL;
        const int s = sb + sl;
        const float px = grids[(g * 3 + 0) * S_ + s];
        const float py = grids[(g * 3 + 1) * S_ + s];
        const float pz = grids[(g * 3 + 2) * S_ + s];
        const float* Ev = Em + vL * 12;
        const float pi0 = Ev[0] * px + Ev[1] * py + Ev[2] * pz + Ev[3];
        const float pi1 = Ev[4] * px + Ev[5] * py + Ev[6] * pz + Ev[7];
        float z = Ev[8] * px + Ev[9] * py + Ev[10] * pz + Ev[11];
        if (fabsf(z) < VFS_EPS) z = 1.0f;
        const float xn = pi0 / z;
        const float yn = pi1 / z;
        const float r2 = xn * xn + yn * yn;
        const float fd = 1.0f + dst[vL * 2 + 0] * r2 + dst[vL * 2 + 1] * r2 * r2;
        const float xd = xn * fd, yd = yn * fd;
        const float* Kv = Km + vL * 9;
        const float pk0 = Kv[0] * xd + Kv[1] * yd + Kv[2];
        const float pk1 = Kv[3] * xd + Kv[4] * yd + Kv[5];
        const float u = 2.0f * pk0 / (W_ - 1.0f) - 1.0f;
        const float vq = 2.0f * pk1 / (H_ - 1.0f) - 1.0f;
        const bool inside = (u >= -1.0f) && (u <= 1.0f) && (vq >= -1.0f) && (vq <= 1.0f);
        const float x = (u + 1.0f) * (W_ * 0.5f) - 0.5f;
        const float y = (vq + 1.0f) * (H_ * 0.5f) - 0.5f;
        const float x0f = floorf(x), y0f = floorf(y);
        const float wx = x - x0f, wy = y - y0f;
        const int x0 = (int)x0f, y0 = (int)y0f;
        const float dx = px - cc[vL * 3 + 0];
        const float dy = py - cc[vL * 3 + 1];
        const float dz = pz - cc[vL * 3 + 2];
        float nrm = sqrtf(dx * dx + dy * dy + dz * dz);
        nrm = fmaxf(nrm, 1e-12f);
        float cosv = (dx * nx + dy * ny + dz * nz) / nrm;
        cosv = fminf(cosv, 0.0f);
        const float wraw = vis[vL * G_ + g] * (-cosv) * (inside ? 1.0f : 0.0f);
        const float bx = 50.0f * wraw;
        float w = (bx > 5.0f) ? wraw : (log1pf(expf(bx)) * (1.0f / 50.0f));
        float wsum = w;
        wsum += __shfl_xor(wsum, 1);
        wsum += __shfl_xor(wsum, 2);
        wsum += __shfl_xor(wsum, 4);
        w = w / wsum;
        wp[sl][vL] = make_float4(__int_as_float(x0), __int_as_float(y0), wx, wy);
        wv[sl][vL] = w;
    }
    __syncthreads();

    float mean[16], var[16];
#pragma unroll 2
    for (int j = 0; j < 16; ++j) {
        const int sl = wave * 16 + j;
        float m = 0.0f, m2 = 0.0f;
#pragma unroll
        for (int v = 0; v < 8; ++v) {
            const float4 q = wp[sl][v];
            const float w = wv[sl][v];
            const int x0 = __float_as_int(q.x);
            const int y0 = __float_as_int(q.y);
            const float wx = q.z, wy = q.w;
            const bool vx0 = (x0 >= 0) & (x0 < W_);
            const bool vx1 = (x0 >= -1) & (x0 < W_ - 1);
            const bool vy0 = (y0 >= 0) & (y0 < H_);
            const bool vy1 = (y0 >= -1) & (y0 < H_ - 1);
            const int xc0 = min(max(x0, 0), W_ - 1);
            const int xc1 = min(max(x0 + 1, 0), W_ - 1);
            const int yc0 = min(max(y0, 0), H_ - 1);
            const int yc1 = min(max(y0 + 1, 0), H_ - 1);
            const float* base = feat + (size_t)v * ((size_t)HW_ * F_) + (size_t)lane * HW_;
            const float g00 = base[(size_t)(yc0 * W_ + xc0)];
            const float g01 = base[(size_t)(yc0 * W_ + xc1)];
            const float g10 = base[(size_t)(yc1 * W_ + xc0)];
            const float g11 = base[(size_t)(yc1 * W_ + xc1)];
            const float f00 = (vx0 & vy0) ? (1.f - wx) * (1.f - wy) : 0.f;
            const float f01 = (vx1 & vy0) ? wx * (1.f - wy) : 0.f;
            const float f10 = (vx0 & vy1) ? (1.f - wx) * wy : 0.f;
            const float f11 = (vx1 & vy1) ? wx * wy : 0.f;
            const float fe = g00 * f00 + g01 * f01 + g10 * f10 + g11 * f11;
            m += w * fe;
            m2 += w * fe * fe;
        }
        mean[j] = m;
        var[j] = m2 - m * m;
    }

#pragma unroll
    for (int j = 0; j < 16; ++j) stg[wave * 16 + j][lane] = mean[j];
    __syncthreads();
#pragma unroll
    for (int i = 0; i < 16; ++i) {
        const int e = t + i * 256;
        const int f = e >> 6;
        const int sl = e & 63;
        out[((size_t)(g * 2 * F_ + f)) * S_ + sb + sl] = stg[sl][f];
    }
    __syncthreads();
#pragma unroll
    for (int j = 0; j < 16; ++j) stg[wave * 16 + j][lane] = var[j];
    __syncthreads();
#pragma unroll
    for (int i = 0; i < 16; ++i) {
        const int e = t + i * 256;
        const int f = e >> 6;
        const int sl = e & 63;
        out[((size_t)(g * 2 * F_ + F_ + f)) * S_ + sb + sl] = stg[sl][f];
    }
}

extern "C" void kernel_launch(void* const* d_in, const int* in_sizes, int n_in,
                              void* d_out, int out_size, void* d_ws, size_t ws_size,
                              hipStream_t stream) {
    const float* fm      = (const float*)d_in[0]; // [1][8][64][256][256]
    const float* Km      = (const float*)d_in[1]; // [1][8][3][3]
    const float* Em      = (const float*)d_in[2]; // [1][8][3][4]
    const float* dist    = (const float*)d_in[3]; // [1][8][2]
    const float* grids   = (const float*)d_in[4]; // [1][128][3][8][8][8]
    const float* vis     = (const float*)d_in[5]; // [1][8][128]
    const float* normals = (const float*)d_in[6]; // [1][128][3]
    const float* cc      = (const float*)d_in[7]; // [1][8][3]
    float* out           = (float*)d_out;         // [1][128][128][8][8][8]

    const size_t tsize = (size_t)V_ * F_ * HW_ * sizeof(__half); // 67 MB
    if (ws_size >= tsize) {
        vfs_transpose_h<<<dim3(HW_ / TPX, V_), 512, 0, stream>>>(fm, (__half*)d_ws);
        vfs_sampler_h2<<<G_ * 8, 256, 0, stream>>>((const __half*)d_ws, Km, Em, dist,
                                                   grids, vis, normals, cc, out);
    } else {
        vfs_sampler_f32<<<G_ * 8, 256, 0, stream>>>(fm, Km, Em, dist,
                                                    grids, vis, normals, cc, out);
    }
}